// Round 1
// baseline (364.631 us; speedup 1.0000x reference)
//
#include <hip/hip_runtime.h>
#include <hip/hip_bf16.h>
#include <stdint.h>

typedef __bf16 bf16_t;
typedef __bf16 bf16x8 __attribute__((ext_vector_type(8)));
typedef float  f32x4  __attribute__((ext_vector_type(4)));
// deliberately under-aligned vector types: addresses are only 4B-aligned
typedef float  f32x4u __attribute__((ext_vector_type(4), aligned(4)));
typedef float  f32x2u __attribute__((ext_vector_type(2), aligned(4)));

constexpr int kOH = 222, kOW = 222;
constexpr int kS    = kOH * kOW;       // 49284 positions per (b,c) plane
constexpr int kCin  = 32, kH = 224, kW = 224;
constexpr int kCout = 64;
constexpr int kKdim = 288;             // C_in * 9, K-permuted tap-major: k' = tap*32 + t
constexpr int kB    = 16;
constexpr int kM    = kB * kS;         // 788544 output rows
constexpr int kBM   = 64;              // rows per block
constexpr int kTapStride = kBM * 32;   // 2048 elems per tap plane in LDS

// weights fp32 [288][64] -> wt bf16 [64][288], K reordered tap-major:
// wt[n*288 + tap*32 + t] = w[(t*9 + tap)*64 + n]
__global__ void prep_weights(const float* __restrict__ w, bf16_t* __restrict__ wt) {
    int e = blockIdx.x * 256 + threadIdx.x;
    if (e >= kCout * kKdim) return;
    int n  = e / kKdim, kp = e - n * kKdim;
    int tap = kp >> 5, t = kp & 31;
    wt[e] = (bf16_t)w[(t * 9 + tap) * kCout + n];
}

__global__ __launch_bounds__(256, 4) void conv_mfma(
        const float* __restrict__ x, const bf16_t* __restrict__ wt,
        const float* __restrict__ bias, float* __restrict__ out) {
    // [tap][row][32] bf16, rows = 64B -> b128 accesses conflict-free & 16B-aligned
    __shared__ __align__(16) bf16_t sA[9 * kTapStride];

    const int tid = threadIdx.x;
    const int m0  = blockIdx.x * kBM;

    // ---- stage A tile: tap-major planes, vectorized (1 group of 8 positions/thread) ----
    {
        const int r  = tid >> 2;            // row in tile (0..63)
        const int t0 = (tid & 3) * 8;       // position-group start within row
        const int m  = m0 + r;
        const int b  = m / kS;
        const int s  = m - b * kS;
        const int P0 = s * 32 + t0;         // linear position in (c,pp) space
        const int c  = P0 / kS;
        const int pp = P0 - c * kS;
        const int ii = pp / kOW;
        const int jj = pp - ii * kOW;
        const float* xb = x + (((b * kCin + c) * kH) + ii) * kW + jj;
        // group wraps an image row iff jj >= 215; at most one wrap per 8-group
        const bool wrap = (jj > kOW - 8);
        const int  E    = kOW - jj;         // first wrapped element index (1..7)
        // address skip at the wrap: row wrap skips cols {222,223} (=2);
        // channel wrap (ii==221) additionally skips 2 full rows (=450)
        const int  skip = (ii == kOW - 1) ? (2 + 2 * kW) : 2;

        #pragma unroll
        for (int di = 0; di < 3; ++di) {
            const float* pr = xb + di * kW;
            f32x4u w0 = *(const f32x4u*)pr;
            f32x4u w1 = *(const f32x4u*)(pr + 4);
            f32x2u w2 = *(const f32x2u*)(pr + 8);
            float a[10] = {w0[0], w0[1], w0[2], w0[3],
                           w1[0], w1[1], w1[2], w1[3],
                           w2[0], w2[1]};
            float aw[10];
            if (wrap) {
                const float* pw = pr + skip;
                f32x4u u0 = *(const f32x4u*)pw;
                f32x4u u1 = *(const f32x4u*)(pw + 4);
                f32x2u u2 = *(const f32x2u*)(pw + 8);
                aw[0]=u0[0]; aw[1]=u0[1]; aw[2]=u0[2]; aw[3]=u0[3];
                aw[4]=u1[0]; aw[5]=u1[1]; aw[6]=u1[2]; aw[7]=u1[3];
                aw[8]=u2[0]; aw[9]=u2[1];
            }
            #pragma unroll
            for (int dj = 0; dj < 3; ++dj) {
                bf16x8 bv;
                #pragma unroll
                for (int e = 0; e < 8; ++e) bv[e] = (bf16_t)a[dj + e];
                if (wrap) {
                    #pragma unroll
                    for (int e = 1; e < 8; ++e)
                        if (e >= E) bv[e] = (bf16_t)aw[dj + e];
                }
                *(bf16x8*)(sA + (di * 3 + dj) * kTapStride + r * 32 + t0) = bv;
            }
        }
    }

    // ---- each wave preloads its 16 weight rows as 9 A-fragments (L2-hot, 36.9 KB) ----
    const int wv   = tid >> 6;        // wave 0..3 -> n-tile
    const int lane = tid & 63;
    const int lc   = lane & 15;
    const int q    = lane >> 4;

    bf16x8 afr[9];
    #pragma unroll
    for (int ks = 0; ks < 9; ++ks)
        afr[ks] = *(const bf16x8*)(wt + (wv * 16 + lc) * kKdim + ks * 32 + q * 8);

    __syncthreads();

    // ---- MFMA: A=weights (rows n), B=pixels (cols s); K-steps = taps ----
    f32x4 acc[4] = {};
    #pragma unroll
    for (int pg = 0; pg < 4; ++pg) {
        const bf16_t* bx = sA + (pg * 16 + lc) * 32 + q * 8;
        #pragma unroll
        for (int ks = 0; ks < 9; ++ks) {
            bf16x8 bfrag = *(const bf16x8*)(bx + ks * kTapStride);
            acc[pg] = __builtin_amdgcn_mfma_f32_16x16x32_bf16(afr[ks], bfrag, acc[pg], 0, 0, 0);
        }
    }

    // ---- epilogue: col(lane&15)=pixel -> coalesced streaming stores over s ----
    const f32x4 bv4 = *(const f32x4*)(bias + wv * 16 + q * 4);
    #pragma unroll
    for (int pg = 0; pg < 4; ++pg) {
        int m = m0 + pg * 16 + lc;
        int b = m / kS;
        int s = m - b * kS;
        float* op = out + (b * kCout + wv * 16 + q * 4) * kS + s;
        #pragma unroll
        for (int reg = 0; reg < 4; ++reg)
            __builtin_nontemporal_store(acc[pg][reg] + bv4[reg], op + reg * kS);
    }
}

extern "C" void kernel_launch(void* const* d_in, const int* in_sizes, int n_in,
                              void* d_out, int out_size, void* d_ws, size_t ws_size,
                              hipStream_t stream) {
    (void)in_sizes; (void)n_in; (void)out_size; (void)ws_size;
    const float* x    = (const float*)d_in[0];
    const float* w    = (const float*)d_in[1];
    const float* bias = (const float*)d_in[2];
    float*       out  = (float*)d_out;
    bf16_t*      wt   = (bf16_t*)d_ws;   // 64*288*2 = 36864 B

    prep_weights<<<(kCout * kKdim + 255) / 256, 256, 0, stream>>>(w, wt);
    conv_mfma<<<kM / kBM, 256, 0, stream>>>(x, wt, bias, out);
}

// Round 3
// 333.838 us; speedup vs baseline: 1.0922x; 1.0922x over previous
//
#include <hip/hip_runtime.h>
#include <hip/hip_bf16.h>
#include <stdint.h>

typedef __bf16 bf16_t;
typedef __bf16 bf16x8 __attribute__((ext_vector_type(8)));
typedef float  f32x4  __attribute__((ext_vector_type(4)));
typedef float  f32x4u __attribute__((ext_vector_type(4), aligned(4)));
typedef float  f32x2u __attribute__((ext_vector_type(2), aligned(4)));

constexpr int kOH = 222, kOW = 222;
constexpr int kS    = kOH * kOW;       // 49284 positions per (b,c) plane
constexpr int kCin  = 32, kH = 224, kW = 224;
constexpr int kCout = 64;
constexpr int kKdim = 288;             // tap-major K: k' = tap*32 + t
constexpr int kB    = 16;
constexpr int kM    = kB * kS;         // 788544 output rows
constexpr int kBM   = 64;              // rows per tile
constexpr int kT    = 3;               // tiles per block (788544 = 4107*192)
constexpr int kTapBytes = kBM * 32 * 2;  // 4096 B per tap plane in LDS

// weights fp32 [288][64] -> wt bf16 [64][288], K reordered tap-major:
// wt[n*288 + tap*32 + t] = w[(t*9 + tap)*64 + n]
__global__ void prep_weights(const float* __restrict__ w, bf16_t* __restrict__ wt) {
    int e = blockIdx.x * 256 + threadIdx.x;
    if (e >= kCout * kKdim) return;
    int n  = e / kKdim, kp = e - n * kKdim;
    int tap = kp >> 5, t = kp & 31;
    wt[e] = (bf16_t)w[(t * 9 + tap) * kCout + n];
}

// register-staged tile state (T14 async-STAGE split: issue early, write late)
struct Stage {
    f32x4u v0[3], v1[3];   // cols jj+0..3, jj+4..7 per tap-row
    f32x2u v2[3];          // cols jj+8..9
    f32x2u vx[3];          // cols jj+10..11 (loaded only on row-wrap)
    const float* xb;
    int  E;
    bool wrap, cwrap;
};

__global__ __launch_bounds__(256, 4) void conv_mfma(
        const float* __restrict__ x, const bf16_t* __restrict__ wt,
        const float* __restrict__ bias, float* __restrict__ out) {
    // [tap][row][32] bf16, 64 B rows, XOR-swizzled 16 B slots
    __shared__ __align__(16) bf16_t sA[9 * kBM * 32];

    const int tid  = threadIdx.x;
    const int r    = tid >> 2;          // staging row in tile (0..63)
    const int g    = tid & 3;           // position-group (t0 = g*8)
    const int t0   = g * 8;
    const int wv   = tid >> 6;          // wave -> n-tile
    const int lane = tid & 63;
    const int lc   = lane & 15;
    const int q    = lane >> 4;
    const int m0   = blockIdx.x * (kBM * kT);

    // swizzled LDS write base: slot = g ^ ((r>>1)&3)
    char* wptr = (char*)sA + r * 64 + ((g ^ ((r >> 1) & 3)) << 4);

    // ---- weights: 9 A-fragments per wave (global, L2-hot, reused kT tiles) ----
    bf16x8 afr[9];
    #pragma unroll
    for (int ks = 0; ks < 9; ++ks)
        afr[ks] = *(const bf16x8*)(wt + (wv * 16 + lc) * kKdim + ks * 32 + q * 8);

    const f32x4 bv4 = *(const f32x4*)(bias + wv * 16 + q * 4);

    Stage st;
    // ---- issue global loads for a tile (reg-staged prefetch) ----
    auto issue = [&](int tm0) {
        int m  = tm0 + r;
        int b  = m / kS;
        int s  = m - b * kS;
        int P0 = s * 32 + t0;           // linear (c,pp) position
        int c  = P0 / kS;
        int pp = P0 - c * kS;
        int ii = pp / kOW;
        int jj = pp - ii * kOW;
        const float* xb = x + (((b * kCin + c) * kH) + ii) * kW + jj;
        st.xb    = xb;
        st.wrap  = (jj > kOW - 8);
        st.cwrap = st.wrap && (ii == kOW - 1);
        st.E     = kOW - jj;
        #pragma unroll
        for (int di = 0; di < 3; ++di) {
            const float* pr = xb + di * kW;
            st.v0[di] = *(const f32x4u*)pr;
            st.v1[di] = *(const f32x4u*)(pr + 4);
            st.v2[di] = *(const f32x2u*)(pr + 8);
        }
        if (st.wrap && !st.cwrap) {
            // row-wrap: +2 shift stays inside a 12-col window; cols jj+10..11
            // stay in-plane (ii<221), so this never runs past the tensor.
            #pragma unroll
            for (int di = 0; di < 3; ++di)
                st.vx[di] = *(const f32x2u*)(st.xb + di * kW + 10);
        } else {
            #pragma unroll
            for (int di = 0; di < 3; ++di) st.vx[di] = f32x2u{0.0f, 0.0f};
        }
    };

    // ---- cvt + select + swizzled LDS write for the staged tile ----
    auto stage_lds = [&]() {
        #pragma unroll
        for (int di = 0; di < 3; ++di) {
            float a[12];
            a[0] = st.v0[di][0]; a[1] = st.v0[di][1];
            a[2] = st.v0[di][2]; a[3] = st.v0[di][3];
            a[4] = st.v1[di][0]; a[5] = st.v1[di][1];
            a[6] = st.v1[di][2]; a[7] = st.v1[di][3];
            a[8] = st.v2[di][0]; a[9] = st.v2[di][1];
            a[10] = st.vx[di][0]; a[11] = st.vx[di][1];
            bf16x8 bvs[3];
            #pragma unroll
            for (int dj = 0; dj < 3; ++dj) {
                #pragma unroll
                for (int e = 0; e < 8; ++e) {
                    float v = a[dj + e];
                    if (st.wrap && e >= st.E) v = a[dj + e + 2];  // row-wrap shift
                    bvs[dj][e] = (bf16_t)v;
                }
            }
            if (st.cwrap) {
                // channel wrap (ii==221 && jj>214): far window at +2+2*kW
                const float* pw = st.xb + di * kW + (2 + 2 * kW);
                f32x4u u0 = *(const f32x4u*)pw;
                f32x4u u1 = *(const f32x4u*)(pw + 4);
                f32x2u u2 = *(const f32x2u*)(pw + 8);
                float aw[10] = {u0[0], u0[1], u0[2], u0[3],
                                u1[0], u1[1], u1[2], u1[3], u2[0], u2[1]};
                #pragma unroll
                for (int dj = 0; dj < 3; ++dj)
                    #pragma unroll
                    for (int e = 1; e < 8; ++e)
                        if (e >= st.E) bvs[dj][e] = (bf16_t)aw[dj + e];
            }
            #pragma unroll
            for (int dj = 0; dj < 3; ++dj)
                *(bf16x8*)(wptr + (di * 3 + dj) * kTapBytes) = bvs[dj];
        }
    };

    issue(m0);                                  // prologue prefetch

    for (int t = 0; t < kT; ++t) {
        stage_lds();                            // waits on loads(t) here
        __syncthreads();
        if (t + 1 < kT) issue(m0 + (t + 1) * kBM);   // prefetch next tile

        // ---- MFMA: A=weights, B=pixels; swizzled ds_read_b128 ----
        f32x4 acc[4] = {};
        #pragma unroll
        for (int pg = 0; pg < 4; ++pg) {
            const char* bx = (const char*)sA + (pg * 16 + lc) * 64
                           + ((q ^ ((lc >> 1) & 3)) << 4);
            #pragma unroll
            for (int ks = 0; ks < 9; ++ks) {
                bf16x8 bfrag = *(const bf16x8*)(bx + ks * kTapBytes);
                acc[pg] = __builtin_amdgcn_mfma_f32_16x16x32_bf16(afr[ks], bfrag, acc[pg], 0, 0, 0);
            }
        }

        // ---- epilogue: plain stores (let L2 combine full lines) ----
        const int tm0 = m0 + t * kBM;
        #pragma unroll
        for (int pg = 0; pg < 4; ++pg) {
            int m = tm0 + pg * 16 + lc;
            int b = m / kS;
            int s = m - b * kS;
            float* op = out + (b * kCout + wv * 16 + q * 4) * kS + s;
            #pragma unroll
            for (int reg = 0; reg < 4; ++reg)
                op[reg * kS] = acc[pg][reg] + bv4[reg];
        }
        __syncthreads();                        // sA reusable next iter
    }
}

extern "C" void kernel_launch(void* const* d_in, const int* in_sizes, int n_in,
                              void* d_out, int out_size, void* d_ws, size_t ws_size,
                              hipStream_t stream) {
    (void)in_sizes; (void)n_in; (void)out_size; (void)ws_size;
    const float* x    = (const float*)d_in[0];
    const float* w    = (const float*)d_in[1];
    const float* bias = (const float*)d_in[2];
    float*       out  = (float*)d_out;
    bf16_t*      wt   = (bf16_t*)d_ws;   // 64*288*2 = 36864 B

    prep_weights<<<(kCout * kKdim + 255) / 256, 256, 0, stream>>>(w, wt);
    conv_mfma<<<kM / (kBM * kT), 256, 0, stream>>>(x, wt, bias, out);
}